// Round 16
// baseline (294.391 us; speedup 1.0000x reference)
//
#include <hip/hip_runtime.h>
#include <hip/hip_bf16.h>

#define N_NODES 50000
#define N_EDGES 800000
#define N_GRAPHS 500
#define IN_DIM 128
#define EXTRA 32
#define HID 64
#define HEADS 4
#define F2 256   /* HEADS*HID */
#define NODES_PER_GRAPH 100
#define SCAN_BLOCKS ((N_NODES + 1023) / 1024)   /* 49 */
#define GEMM_BLKS 782                            /* ceil(50000/64) */
#define SCAT_BLKS 3125                           /* ceil(800000/256) */

typedef unsigned short u16;
typedef __attribute__((ext_vector_type(8))) short short8;     // 8 bf16 = 4 VGPR
typedef __attribute__((ext_vector_type(4))) float floatx4;    // MFMA C/D frag

__device__ __forceinline__ float bf2f(u16 u) {
    union { unsigned int i; float f; } v;
    v.i = ((unsigned int)u) << 16;
    return v.f;
}
__device__ __forceinline__ u16 f2b(float f) {
    __hip_bfloat16 h = __float2bfloat16(f);
    return *reinterpret_cast<u16*>(&h);
}

// ---------------- prep0: Wal2[c][q] = sum_j W2[c][h*64+j] * {al2,ar2}[h][j], q = h*2+lr ----------------
__global__ __launch_bounds__(256) void prep0_kernel(const float* __restrict__ W2,
                                                    const float* __restrict__ al2,
                                                    const float* __restrict__ ar2,
                                                    float* __restrict__ Wal2) {
    int c = threadIdx.x;
    const float* wr = W2 + (size_t)c * 256;
    float acc[8] = {0.f};
#pragma unroll
    for (int h = 0; h < 4; ++h)
        for (int j = 0; j < 64; ++j) {
            float wv = wr[h * 64 + j];
            acc[h * 2 + 0] = fmaf(wv, al2[h * 64 + j], acc[h * 2 + 0]);
            acc[h * 2 + 1] = fmaf(wv, ar2[h * 64 + j], acc[h * 2 + 1]);
        }
#pragma unroll
    for (int q = 0; q < 8; ++q) Wal2[c * 8 + q] = acc[q];
}

// ---------------- fused prep: edge-count+rank | x->bf16 | W1/W2 repack ----------------
#define CNT_BLK 3125
#define CVT_BLK 6250
#define RP1_BLK 16
#define RP2_BLK 32
__global__ __launch_bounds__(256) void prep_kernel(const int* __restrict__ dst,
                                                   int* __restrict__ cnt,
                                                   int* __restrict__ rank,
                                                   const float* __restrict__ x,
                                                   u16* __restrict__ xb,
                                                   const float* __restrict__ W1,
                                                   u16* __restrict__ BF1,
                                                   const float* __restrict__ W2,
                                                   u16* __restrict__ BF2) {
    int b = blockIdx.x, t = threadIdx.x;
    if (b < CNT_BLK) {
        int e = b * 256 + t;
        if (e < N_EDGES) rank[e] = atomicAdd(&cnt[dst[e]], 1);
    } else if (b < CNT_BLK + CVT_BLK) {
        int i = (b - CNT_BLK) * 256 + t;   // float4 index
        float4 v = reinterpret_cast<const float4*>(x)[i];
        ushort4 o;
        o.x = f2b(v.x); o.y = f2b(v.y); o.z = f2b(v.z); o.w = f2b(v.w);
        reinterpret_cast<ushort4*>(xb)[i] = o;
    } else {
        const float* W;
        u16* BF;
        int chunk;
        if (b < CNT_BLK + CVT_BLK + RP1_BLK) {
            W = W1; BF = BF1; chunk = (b - CNT_BLK - CVT_BLK) * 4 + (t >> 6);
        } else {
            W = W2; BF = BF2; chunk = (b - CNT_BLK - CVT_BLK - RP1_BLK) * 4 + (t >> 6);
        }
        int l = t & 63;
        int kt = chunk >> 4, ct = chunk & 15;
        int col = ct * 16 + (l & 15);
        int k0 = kt * 32 + 8 * (l >> 4);
        u16* p = BF + (size_t)chunk * 512 + l * 8;
#pragma unroll
        for (int j = 0; j < 8; ++j) p[j] = f2b(W[(size_t)(k0 + j) * 256 + col]);
    }
}

// ---------------- CSR scan ----------------
__global__ __launch_bounds__(1024) void scan_block_kernel(const int* __restrict__ cnt,
                                                          int* __restrict__ part,
                                                          int* __restrict__ bsum) {
    __shared__ int buf[1024];
    int b = blockIdx.x, t = threadIdx.x;
    int i = b * 1024 + t;
    buf[t] = (i < N_NODES) ? cnt[i] : 0;
    __syncthreads();
    for (int d = 1; d < 1024; d <<= 1) {
        int add = (t >= d) ? buf[t - d] : 0;
        __syncthreads();
        buf[t] += add;
        __syncthreads();
    }
    if (i < N_NODES) part[i] = buf[t];
    if (t == 1023) bsum[b] = buf[t];
}

// finalize offs AND fill csr_dst (each thread fills its node's contiguous segment)
__global__ __launch_bounds__(1024) void scan_finalize_kernel(const int* __restrict__ part,
                                                             const int* __restrict__ bsum,
                                                             int* __restrict__ offs,
                                                             int* __restrict__ csr_dst) {
    __shared__ int sb;
    int t = threadIdx.x;
    if (t < 64) {
        int v = (t < blockIdx.x) ? bsum[t] : 0;   // SCAN_BLOCKS=49 <= 64
#pragma unroll
        for (int d = 32; d > 0; d >>= 1) v += __shfl_xor(v, d);
        if (t == 0) sb = v;
    }
    __syncthreads();
    int sbase = sb;
    int i = blockIdx.x * 1024 + t;
    if (i < N_NODES) {
        int hi = part[i] + sbase;
        offs[i + 1] = hi;
        if (i == 0) offs[0] = 0;
        int lo = (t == 0) ? sbase : part[i - 1] + sbase;
        for (int p = lo; p < hi; ++p) csr_dst[p] = i;   // contiguous per-node segment
    }
}

// ---------------- MFMA GEMM + attention epilogue body (register-resident B) ----------------
template <int K>
__device__ __forceinline__ void gemm_attn_body(int bx, const u16* __restrict__ A,
                                               const u16* __restrict__ BF,
                                               const float* __restrict__ al,
                                               const float* __restrict__ ar,
                                               u16* __restrict__ C,
                                               float* __restrict__ el,
                                               float* __restrict__ er, int M) {
    const int NKT = K / 32;
    __shared__ u16 cxpose[4][16 * 68];  // per-wave C-transpose buf (no barriers needed)
    int t = threadIdx.x;
    int wave = t >> 6, lane = t & 63;
    int l15 = lane & 15, kg = lane >> 4;
    int h = wave;                       // wave == head == col group
    int ct0 = h * 4;

    short8 breg[NKT][4];
#pragma unroll
    for (int kt = 0; kt < NKT; ++kt)
#pragma unroll
        for (int c = 0; c < 4; ++c)
            breg[kt][c] = *reinterpret_cast<const short8*>(
                              BF + (size_t)(kt * 16 + ct0 + c) * 512 + lane * 8);

    float alv[4], arv[4];
#pragma unroll
    for (int c = 0; c < 4; ++c) {
        alv[c] = al[(ct0 + c) * 16 + l15];
        arv[c] = ar[(ct0 + c) * 16 + l15];
    }

    u16* cbuf = cxpose[wave];
    for (int rt = 0; rt < 4; ++rt) {
        int row0 = bx * 64 + rt * 16;
        if (row0 >= M) break;
        int arow = row0 + l15; if (arow >= M) arow = M - 1;   // clamp; stores guarded
        const u16* Ap = A + (size_t)arow * K + kg * 8;

        floatx4 acc[4];
#pragma unroll
        for (int c = 0; c < 4; ++c) acc[c] = (floatx4)0.0f;
#pragma unroll
        for (int kt = 0; kt < NKT; ++kt) {
            short8 a = *reinterpret_cast<const short8*>(Ap + kt * 32);
#pragma unroll
            for (int c = 0; c < 4; ++c)
                acc[c] = __builtin_amdgcn_mfma_f32_16x16x32_bf16(a, breg[kt][c], acc[c], 0, 0, 0);
        }

        floatx4 pl = (floatx4)0.0f, pr = (floatx4)0.0f;
#pragma unroll
        for (int c = 0; c < 4; ++c) {
            pl += acc[c] * alv[c];
            pr += acc[c] * arv[c];
        }
#pragma unroll
        for (int off = 1; off < 16; off <<= 1) {
#pragma unroll
            for (int j = 0; j < 4; ++j) {
                pl[j] += __shfl_xor(pl[j], off);
                pr[j] += __shfl_xor(pr[j], off);
            }
        }
        if (l15 == 0) {
#pragma unroll
            for (int j = 0; j < 4; ++j) {
                int n = row0 + kg * 4 + j;
                if (n < M) { el[n * 4 + h] = pl[j]; er[n * 4 + h] = pr[j]; }
            }
        }

#pragma unroll
        for (int c = 0; c < 4; ++c)
#pragma unroll
            for (int j = 0; j < 4; ++j)
                cbuf[(kg * 4 + j) * 68 + c * 16 + l15] = f2b(acc[c][j]);
#pragma unroll
        for (int it = 0; it < 2; ++it) {
            int r = (lane >> 3) + it * 8;
            int cg = lane & 7;
            int grow = row0 + r;
            if (grow < M) {
                short8 v = *reinterpret_cast<const short8*>(cbuf + r * 68 + cg * 8);
                *reinterpret_cast<short8*>(C + (size_t)grow * 256 + h * 64 + cg * 8) = v;
            }
        }
    }
}

// ---------------- edge-weight body (CSR order, coalesced) ----------------
__device__ __forceinline__ void edge_w_body(int e, const int* __restrict__ csr_src,
                                            const int* __restrict__ csr_dst,
                                            const float* __restrict__ el,
                                            const float* __restrict__ er,
                                            float* __restrict__ w) {
    if (e >= N_EDGES) return;
    int s = csr_src[e], d = csr_dst[e];
    float4 l = *reinterpret_cast<const float4*>(&el[s * 4]);
    float4 r = *reinterpret_cast<const float4*>(&er[d * 4]);
    float4 o; float v;
    v = l.x + r.x; v = (v > 0.f) ? v : 0.2f * v; o.x = __expf(v);
    v = l.y + r.y; v = (v > 0.f) ? v : 0.2f * v; o.y = __expf(v);
    v = l.z + r.z; v = (v > 0.f) ? v : 0.2f * v; o.z = __expf(v);
    v = l.w + r.w; v = (v > 0.f) ? v : 0.2f * v; o.w = __expf(v);
    *reinterpret_cast<float4*>(&w[(size_t)e * 4]) = o;
}

// ---------------- fused gemm1 + scatter (atomic-free: pos = offs[d] + rank[e]) ----------------
__global__ __launch_bounds__(256) void gemm1_scatter_kernel(const u16* __restrict__ A,
                                                            const u16* __restrict__ BF,
                                                            const float* __restrict__ al,
                                                            const float* __restrict__ ar,
                                                            u16* __restrict__ C,
                                                            float* __restrict__ el,
                                                            float* __restrict__ er,
                                                            const int* __restrict__ src,
                                                            const int* __restrict__ dst,
                                                            const int* __restrict__ offs,
                                                            const int* __restrict__ rank,
                                                            int* __restrict__ csr_src) {
    int b = blockIdx.x;
    int g = b / 5, r = b - g * 5;
    if (r == 0) {
        gemm_attn_body<IN_DIM>(g, A, BF, al, ar, C, el, er, N_NODES);
    } else {
        int e = (b - g - 1) * 256 + threadIdx.x;
        if (e < N_EDGES) {
            int d = dst[e];
            csr_src[offs[d] + rank[e]] = src[e];   // no atomics: rank from prep's count pass
        }
    }
}

// ---------------- fused gemm2 + edge_w2 (el2/er2 already computed by gather1) ----------------
__global__ __launch_bounds__(256) void gemm2_edgew_kernel(const u16* __restrict__ A,
                                                          const u16* __restrict__ BF,
                                                          const float* __restrict__ al,
                                                          const float* __restrict__ ar,
                                                          u16* __restrict__ C,
                                                          float* __restrict__ el_dummy,
                                                          float* __restrict__ er_dummy,
                                                          const int* __restrict__ csr_src,
                                                          const int* __restrict__ csr_dst,
                                                          const float* __restrict__ el2,
                                                          const float* __restrict__ er2,
                                                          float* __restrict__ w) {
    int b = blockIdx.x;
    int g = b / 5, r = b - g * 5;
    if (r == 0) {
        gemm_attn_body<F2>(g, A, BF, al, ar, C, el_dummy, er_dummy, N_NODES);
    } else {
        int e = (b - g - 1) * 256 + threadIdx.x;
        edge_w_body(e, csr_src, csr_dst, el2, er2, w);
    }
}

// ---------------- standalone edge weights (layer 1) ----------------
__global__ void edge_w_kernel(const int* __restrict__ csr_src, const int* __restrict__ csr_dst,
                              const float* __restrict__ el, const float* __restrict__ er,
                              float* __restrict__ w) {
    edge_w_body(blockIdx.x * blockDim.x + threadIdx.x, csr_src, csr_dst, el, er, w);
}

// ---------------- gather1: aggregate + el2/er2 epilogue (h1 row in registers) ----------------
// el2[n,h] = h1[n,:] . Wal2[:, h*2], er2 likewise — linear in h1, so computable here,
// which makes edge_w2 independent of gemm2 (overlapped in gemm2_edgew).
__global__ __launch_bounds__(256) void gather1_kernel(const u16* __restrict__ feat,
                                                      const float* __restrict__ w,
                                                      const int* __restrict__ offs,
                                                      const int* __restrict__ csr_src,
                                                      const float* __restrict__ bias,
                                                      const float* __restrict__ Wal2,
                                                      u16* __restrict__ outb,
                                                      float* __restrict__ el2,
                                                      float* __restrict__ er2) {
    __shared__ float wal[256][8];
    {   // stage Wal2 (8 KB), coalesced: thread t loads row t
        const float4* src4 = reinterpret_cast<const float4*>(Wal2 + threadIdx.x * 8);
        *reinterpret_cast<float4*>(&wal[threadIdx.x][0]) = src4[0];
        *reinterpret_cast<float4*>(&wal[threadIdx.x][4]) = src4[1];
    }
    __syncthreads();
    int n = blockIdx.x * 4 + (threadIdx.x >> 6);
    if (n >= N_NODES) return;
    int lane = threadIdx.x & 63;
    int h = lane >> 4;
    const ushort4* feat4 = reinterpret_cast<const ushort4*>(feat);
    int s0 = offs[n], s1 = offs[n + 1];
    float4 acc = make_float4(0.f, 0.f, 0.f, 0.f);
    float den = 0.f;
    int i = s0;
    for (; i + 4 <= s1; i += 4) {
        int n0 = csr_src[i], n1 = csr_src[i + 1], n2 = csr_src[i + 2], n3 = csr_src[i + 3];
        float x0 = w[(size_t)(i + 0) * 4 + h];
        float x1 = w[(size_t)(i + 1) * 4 + h];
        float x2 = w[(size_t)(i + 2) * 4 + h];
        float x3 = w[(size_t)(i + 3) * 4 + h];
        ushort4 f0 = feat4[(size_t)n0 * 64 + lane];
        ushort4 f1 = feat4[(size_t)n1 * 64 + lane];
        ushort4 f2 = feat4[(size_t)n2 * 64 + lane];
        ushort4 f3 = feat4[(size_t)n3 * 64 + lane];
        acc.x = fmaf(x0, bf2f(f0.x), acc.x); acc.y = fmaf(x0, bf2f(f0.y), acc.y);
        acc.z = fmaf(x0, bf2f(f0.z), acc.z); acc.w = fmaf(x0, bf2f(f0.w), acc.w);
        acc.x = fmaf(x1, bf2f(f1.x), acc.x); acc.y = fmaf(x1, bf2f(f1.y), acc.y);
        acc.z = fmaf(x1, bf2f(f1.z), acc.z); acc.w = fmaf(x1, bf2f(f1.w), acc.w);
        acc.x = fmaf(x2, bf2f(f2.x), acc.x); acc.y = fmaf(x2, bf2f(f2.y), acc.y);
        acc.z = fmaf(x2, bf2f(f2.z), acc.z); acc.w = fmaf(x2, bf2f(f2.w), acc.w);
        acc.x = fmaf(x3, bf2f(f3.x), acc.x); acc.y = fmaf(x3, bf2f(f3.y), acc.y);
        acc.z = fmaf(x3, bf2f(f3.z), acc.z); acc.w = fmaf(x3, bf2f(f3.w), acc.w);
        den += (x0 + x1) + (x2 + x3);
    }
    for (; i < s1; ++i) {
        int s = csr_src[i];
        float x = w[(size_t)i * 4 + h];
        ushort4 f = feat4[(size_t)s * 64 + lane];
        acc.x = fmaf(x, bf2f(f.x), acc.x); acc.y = fmaf(x, bf2f(f.y), acc.y);
        acc.z = fmaf(x, bf2f(f.z), acc.z); acc.w = fmaf(x, bf2f(f.w), acc.w);
        den += x;
    }
    float inv = (s1 > s0) ? 1.f / den : 0.f;
    float4 bv = reinterpret_cast<const float4*>(bias)[lane];
    float4 rr;
    rr.x = fmaxf(fmaf(acc.x, inv, bv.x), 0.f);
    rr.y = fmaxf(fmaf(acc.y, inv, bv.y), 0.f);
    rr.z = fmaxf(fmaf(acc.z, inv, bv.z), 0.f);
    rr.w = fmaxf(fmaf(acc.w, inv, bv.w), 0.f);
    ushort4 o;
    o.x = f2b(rr.x); o.y = f2b(rr.y); o.z = f2b(rr.z); o.w = f2b(rr.w);
    reinterpret_cast<ushort4*>(outb)[(size_t)n * 64 + lane] = o;

    // ---- el2/er2 epilogue: 8 full-wave dots with Wal2 ----
    int c0 = lane * 4;
    float p[8];
#pragma unroll
    for (int q = 0; q < 8; ++q)
        p[q] = rr.x * wal[c0][q] + rr.y * wal[c0 + 1][q] +
               rr.z * wal[c0 + 2][q] + rr.w * wal[c0 + 3][q];
#pragma unroll
    for (int off = 1; off < 64; off <<= 1)
#pragma unroll
        for (int q = 0; q < 8; ++q) p[q] += __shfl_xor(p[q], off);
    if (lane == 0) {
        float4 evl = make_float4(p[0], p[2], p[4], p[6]);
        float4 evr = make_float4(p[1], p[3], p[5], p[7]);
        *reinterpret_cast<float4*>(&el2[n * 4]) = evl;
        *reinterpret_cast<float4*>(&er2[n * 4]) = evr;
    }
}

// ---------------- gather2: aggregate only ----------------
__global__ __launch_bounds__(256) void gather_kernel(const u16* __restrict__ feat,
                                                     const float* __restrict__ w,
                                                     const int* __restrict__ offs,
                                                     const int* __restrict__ csr_src,
                                                     const float* __restrict__ bias,
                                                     u16* __restrict__ outb) {
    int n = blockIdx.x * 4 + (threadIdx.x >> 6);
    if (n >= N_NODES) return;
    int lane = threadIdx.x & 63;
    int h = lane >> 4;
    const ushort4* feat4 = reinterpret_cast<const ushort4*>(feat);
    int s0 = offs[n], s1 = offs[n + 1];
    float4 acc = make_float4(0.f, 0.f, 0.f, 0.f);
    float den = 0.f;
    int i = s0;
    for (; i + 4 <= s1; i += 4) {
        int n0 = csr_src[i], n1 = csr_src[i + 1], n2 = csr_src[i + 2], n3 = csr_src[i + 3];
        float x0 = w[(size_t)(i + 0) * 4 + h];
        float x1 = w[(size_t)(i + 1) * 4 + h];
        float x2 = w[(size_t)(i + 2) * 4 + h];
        float x3 = w[(size_t)(i + 3) * 4 + h];
        ushort4 f0 = feat4[(size_t)n0 * 64 + lane];
        ushort4 f1 = feat4[(size_t)n1 * 64 + lane];
        ushort4 f2 = feat4[(size_t)n2 * 64 + lane];
        ushort4 f3 = feat4[(size_t)n3 * 64 + lane];
        acc.x = fmaf(x0, bf2f(f0.x), acc.x); acc.y = fmaf(x0, bf2f(f0.y), acc.y);
        acc.z = fmaf(x0, bf2f(f0.z), acc.z); acc.w = fmaf(x0, bf2f(f0.w), acc.w);
        acc.x = fmaf(x1, bf2f(f1.x), acc.x); acc.y = fmaf(x1, bf2f(f1.y), acc.y);
        acc.z = fmaf(x1, bf2f(f1.z), acc.z); acc.w = fmaf(x1, bf2f(f1.w), acc.w);
        acc.x = fmaf(x2, bf2f(f2.x), acc.x); acc.y = fmaf(x2, bf2f(f2.y), acc.y);
        acc.z = fmaf(x2, bf2f(f2.z), acc.z); acc.w = fmaf(x2, bf2f(f2.w), acc.w);
        acc.x = fmaf(x3, bf2f(f3.x), acc.x); acc.y = fmaf(x3, bf2f(f3.y), acc.y);
        acc.z = fmaf(x3, bf2f(f3.z), acc.z); acc.w = fmaf(x3, bf2f(f3.w), acc.w);
        den += (x0 + x1) + (x2 + x3);
    }
    for (; i < s1; ++i) {
        int s = csr_src[i];
        float x = w[(size_t)i * 4 + h];
        ushort4 f = feat4[(size_t)s * 64 + lane];
        acc.x = fmaf(x, bf2f(f.x), acc.x); acc.y = fmaf(x, bf2f(f.y), acc.y);
        acc.z = fmaf(x, bf2f(f.z), acc.z); acc.w = fmaf(x, bf2f(f.w), acc.w);
        den += x;
    }
    float inv = (s1 > s0) ? 1.f / den : 0.f;
    float4 bv = reinterpret_cast<const float4*>(bias)[lane];
    ushort4 o;
    o.x = f2b(fmaxf(fmaf(acc.x, inv, bv.x), 0.f));
    o.y = f2b(fmaxf(fmaf(acc.y, inv, bv.y), 0.f));
    o.z = f2b(fmaxf(fmaf(acc.z, inv, bv.z), 0.f));
    o.w = f2b(fmaxf(fmaf(acc.w, inv, bv.w), 0.f));
    reinterpret_cast<ushort4*>(outb)[(size_t)n * 64 + lane] = o;
}

// ---------------- fused mean-pool + 3-layer MLP head (bf16 h2) ----------------
__global__ __launch_bounds__(256) void head_kernel(const u16* __restrict__ h2,
                                                   const float* __restrict__ desc,
                                                   const float* __restrict__ fc1_w,
                                                   const float* __restrict__ fc1_b,
                                                   const float* __restrict__ fc2_w,
                                                   const float* __restrict__ fc2_b,
                                                   const float* __restrict__ out_w,
                                                   const float* __restrict__ out_b,
                                                   float* __restrict__ out) {
    __shared__ float comb[288];
    __shared__ float z1[64];
    __shared__ float z2[32];
    int g = blockIdx.x, t = threadIdx.x;
    const u16* base = h2 + (size_t)g * NODES_PER_GRAPH * 256;
    float s0 = 0.f, s1 = 0.f, s2 = 0.f, s3 = 0.f;   // 4 independent load chains
    for (int i = 0; i < NODES_PER_GRAPH; i += 4) {
        s0 += bf2f(base[(size_t)(i + 0) * 256 + t]);
        s1 += bf2f(base[(size_t)(i + 1) * 256 + t]);
        s2 += bf2f(base[(size_t)(i + 2) * 256 + t]);
        s3 += bf2f(base[(size_t)(i + 3) * 256 + t]);
    }
    comb[t] = ((s0 + s1) + (s2 + s3)) * (1.f / NODES_PER_GRAPH);
    if (t < EXTRA) comb[256 + t] = desc[g * EXTRA + t];
    __syncthreads();
    if (t < 64) {
        float a = fc1_b[t];
        for (int i = 0; i < 288; ++i) a += comb[i] * fc1_w[i * 64 + t];
        z1[t] = fmaxf(a, 0.f);
    }
    __syncthreads();
    if (t < 32) {
        float a = fc2_b[t];
        for (int i = 0; i < 64; ++i) a += z1[i] * fc2_w[i * 32 + t];
        z2[t] = fmaxf(a, 0.f);
    }
    __syncthreads();
    if (t == 0) {
        float a = out_b[0];
        for (int i = 0; i < 32; ++i) a += z2[i] * out_w[i];
        out[g] = a;
    }
}

extern "C" void kernel_launch(void* const* d_in, const int* in_sizes, int n_in,
                              void* d_out, int out_size, void* d_ws, size_t ws_size,
                              hipStream_t stream) {
    const float* x     = (const float*)d_in[0];
    const float* desc  = (const float*)d_in[1];
    const int*   src   = (const int*)d_in[2];
    const int*   dst   = (const int*)d_in[3];
    /* d_in[4] graph_id: contiguous (n/100) by construction — unused */
    const float* W1    = (const float*)d_in[5];
    const float* al1   = (const float*)d_in[6];
    const float* ar1   = (const float*)d_in[7];
    const float* b1    = (const float*)d_in[8];
    const float* W2    = (const float*)d_in[9];
    const float* al2   = (const float*)d_in[10];
    const float* ar2   = (const float*)d_in[11];
    const float* b2    = (const float*)d_in[12];
    const float* fc1_w = (const float*)d_in[13];
    const float* fc1_b = (const float*)d_in[14];
    const float* fc2_w = (const float*)d_in[15];
    const float* fc2_b = (const float*)d_in[16];
    const float* out_w = (const float*)d_in[17];
    const float* out_b = (const float*)d_in[18];
    float* out = (float*)d_out;

    char* ws = (char*)d_ws;
    size_t off = 0;
    auto alloc = [&](size_t bytes) -> void* {
        void* p = ws + off;
        off = (off + bytes + 255) & ~(size_t)255;
        return p;
    };
    u16*   xb      = (u16*)alloc((size_t)N_NODES * IN_DIM * 2);
    u16*   featb   = (u16*)alloc((size_t)N_NODES * 256 * 2);
    u16*   h1b     = (u16*)alloc((size_t)N_NODES * 256 * 2);
    u16*   h2b     = (u16*)alloc((size_t)N_NODES * 256 * 2);
    u16*   BF1     = (u16*)alloc((size_t)IN_DIM * 256 * 2);
    u16*   BF2     = (u16*)alloc((size_t)F2 * 256 * 2);
    float* el      = (float*)alloc((size_t)N_NODES * 4 * 4);
    float* er      = (float*)alloc((size_t)N_NODES * 4 * 4);
    float* el2     = (float*)alloc((size_t)N_NODES * 4 * 4);
    float* er2     = (float*)alloc((size_t)N_NODES * 4 * 4);
    float* Wal2    = (float*)alloc((size_t)256 * 8 * 4);
    int*   offs    = (int*)alloc((size_t)(N_NODES + 1) * 4);
    int*   cnt     = (int*)alloc((size_t)N_NODES * 4);
    int*   part    = (int*)alloc((size_t)N_NODES * 4);
    int*   bsum    = (int*)alloc(64 * 4);
    int*   csr_src = (int*)alloc((size_t)N_EDGES * 4);
    int*   csr_dst = (int*)alloc((size_t)N_EDGES * 4);
    int*   rankb   = (int*)alloc((size_t)N_EDGES * 4);
    float* wbuf    = (float*)alloc((size_t)N_EDGES * 4 * 4);

    hipMemsetAsync(cnt, 0, (size_t)N_NODES * 4, stream);
    prep0_kernel<<<1, 256, 0, stream>>>(W2, al2, ar2, Wal2);
    prep_kernel<<<CNT_BLK + CVT_BLK + RP1_BLK + RP2_BLK, 256, 0, stream>>>(
        dst, cnt, rankb, x, xb, W1, BF1, W2, BF2);
    scan_block_kernel<<<SCAN_BLOCKS, 1024, 0, stream>>>(cnt, part, bsum);
    scan_finalize_kernel<<<SCAN_BLOCKS, 1024, 0, stream>>>(part, bsum, offs, csr_dst);

    int eb = (N_EDGES + 255) / 256;
    int ngb = (N_NODES + 3) / 4;
    // layer 1: gemm1 overlapped with atomic-free CSR scatter
    gemm1_scatter_kernel<<<GEMM_BLKS + SCAT_BLKS, 256, 0, stream>>>(
        xb, BF1, al1, ar1, featb, el, er, src, dst, offs, rankb, csr_src);
    edge_w_kernel<<<eb, 256, 0, stream>>>(csr_src, csr_dst, el, er, wbuf);
    gather1_kernel<<<ngb, 256, 0, stream>>>(featb, wbuf, offs, csr_src, b1, Wal2,
                                            h1b, el2, er2);
    // layer 2: gemm2 overlapped with edge_w2 (el2/er2 from gather1)
    gemm2_edgew_kernel<<<GEMM_BLKS + SCAT_BLKS, 256, 0, stream>>>(
        h1b, BF2, al2, ar2, featb, el, er, csr_src, csr_dst, el2, er2, wbuf);
    gather_kernel<<<ngb, 256, 0, stream>>>(featb, wbuf, offs, csr_src, b2, h2b);
    // pool + MLP head
    head_kernel<<<N_GRAPHS, 256, 0, stream>>>(h2b, desc, fc1_w, fc1_b, fc2_w, fc2_b,
                                              out_w, out_b, out);
}

// Round 17
// 281.465 us; speedup vs baseline: 1.0459x; 1.0459x over previous
//
#include <hip/hip_runtime.h>
#include <hip/hip_bf16.h>

#define N_NODES 50000
#define N_EDGES 800000
#define N_GRAPHS 500
#define IN_DIM 128
#define EXTRA 32
#define HID 64
#define HEADS 4
#define F2 256   /* HEADS*HID */
#define NODES_PER_GRAPH 100
#define SCAN_BLOCKS ((N_NODES + 1023) / 1024)   /* 49 */
#define GEMM_BLKS 782                            /* ceil(50000/64) */
#define SCAT_BLKS 3125                           /* ceil(800000/256) */

typedef unsigned short u16;
typedef __attribute__((ext_vector_type(8))) short short8;     // 8 bf16 = 4 VGPR
typedef __attribute__((ext_vector_type(4))) float floatx4;    // MFMA C/D frag

__device__ __forceinline__ float bf2f(u16 u) {
    union { unsigned int i; float f; } v;
    v.i = ((unsigned int)u) << 16;
    return v.f;
}
__device__ __forceinline__ u16 f2b(float f) {
    __hip_bfloat16 h = __float2bfloat16(f);
    return *reinterpret_cast<u16*>(&h);
}

// ---------------- prep0: Wal2[c][q] = sum_j W2[c][h*64+j] * {al2,ar2}[h][j], q = h*2+lr ----------------
__global__ __launch_bounds__(256) void prep0_kernel(const float* __restrict__ W2,
                                                    const float* __restrict__ al2,
                                                    const float* __restrict__ ar2,
                                                    float* __restrict__ Wal2) {
    int c = threadIdx.x;
    const float* wr = W2 + (size_t)c * 256;
    float acc[8] = {0.f};
#pragma unroll
    for (int h = 0; h < 4; ++h)
        for (int j = 0; j < 64; ++j) {
            float wv = wr[h * 64 + j];
            acc[h * 2 + 0] = fmaf(wv, al2[h * 64 + j], acc[h * 2 + 0]);
            acc[h * 2 + 1] = fmaf(wv, ar2[h * 64 + j], acc[h * 2 + 1]);
        }
#pragma unroll
    for (int q = 0; q < 8; ++q) Wal2[c * 8 + q] = acc[q];
}

// ---------------- fused prep: edge-count+rank | x->bf16 | W1/W2 repack ----------------
#define CNT_BLK 3125
#define CVT_BLK 6250
#define RP1_BLK 16
#define RP2_BLK 32
__global__ __launch_bounds__(256) void prep_kernel(const int* __restrict__ dst,
                                                   int* __restrict__ cnt,
                                                   int* __restrict__ rank,
                                                   const float* __restrict__ x,
                                                   u16* __restrict__ xb,
                                                   const float* __restrict__ W1,
                                                   u16* __restrict__ BF1,
                                                   const float* __restrict__ W2,
                                                   u16* __restrict__ BF2) {
    int b = blockIdx.x, t = threadIdx.x;
    if (b < CNT_BLK) {
        int e = b * 256 + t;
        if (e < N_EDGES) rank[e] = atomicAdd(&cnt[dst[e]], 1);
    } else if (b < CNT_BLK + CVT_BLK) {
        int i = (b - CNT_BLK) * 256 + t;   // float4 index
        float4 v = reinterpret_cast<const float4*>(x)[i];
        ushort4 o;
        o.x = f2b(v.x); o.y = f2b(v.y); o.z = f2b(v.z); o.w = f2b(v.w);
        reinterpret_cast<ushort4*>(xb)[i] = o;
    } else {
        const float* W;
        u16* BF;
        int chunk;
        if (b < CNT_BLK + CVT_BLK + RP1_BLK) {
            W = W1; BF = BF1; chunk = (b - CNT_BLK - CVT_BLK) * 4 + (t >> 6);
        } else {
            W = W2; BF = BF2; chunk = (b - CNT_BLK - CVT_BLK - RP1_BLK) * 4 + (t >> 6);
        }
        int l = t & 63;
        int kt = chunk >> 4, ct = chunk & 15;
        int col = ct * 16 + (l & 15);
        int k0 = kt * 32 + 8 * (l >> 4);
        u16* p = BF + (size_t)chunk * 512 + l * 8;
#pragma unroll
        for (int j = 0; j < 8; ++j) p[j] = f2b(W[(size_t)(k0 + j) * 256 + col]);
    }
}

// ---------------- CSR scan ----------------
__global__ __launch_bounds__(1024) void scan_block_kernel(const int* __restrict__ cnt,
                                                          int* __restrict__ part,
                                                          int* __restrict__ bsum) {
    __shared__ int buf[1024];
    int b = blockIdx.x, t = threadIdx.x;
    int i = b * 1024 + t;
    buf[t] = (i < N_NODES) ? cnt[i] : 0;
    __syncthreads();
    for (int d = 1; d < 1024; d <<= 1) {
        int add = (t >= d) ? buf[t - d] : 0;
        __syncthreads();
        buf[t] += add;
        __syncthreads();
    }
    if (i < N_NODES) part[i] = buf[t];
    if (t == 1023) bsum[b] = buf[t];
}

// finalize offs AND fill csr_dst (each thread fills its node's contiguous segment)
__global__ __launch_bounds__(1024) void scan_finalize_kernel(const int* __restrict__ part,
                                                             const int* __restrict__ bsum,
                                                             int* __restrict__ offs,
                                                             int* __restrict__ csr_dst) {
    __shared__ int sb;
    int t = threadIdx.x;
    if (t < 64) {
        int v = (t < blockIdx.x) ? bsum[t] : 0;   // SCAN_BLOCKS=49 <= 64
#pragma unroll
        for (int d = 32; d > 0; d >>= 1) v += __shfl_xor(v, d);
        if (t == 0) sb = v;
    }
    __syncthreads();
    int sbase = sb;
    int i = blockIdx.x * 1024 + t;
    if (i < N_NODES) {
        int hi = part[i] + sbase;
        offs[i + 1] = hi;
        if (i == 0) offs[0] = 0;
        int lo = (t == 0) ? sbase : part[i - 1] + sbase;
        for (int p = lo; p < hi; ++p) csr_dst[p] = i;   // contiguous per-node segment
    }
}

// ---------------- MFMA GEMM + attention epilogue body (register-resident B) ----------------
template <int K>
__device__ __forceinline__ void gemm_attn_body(int bx, const u16* __restrict__ A,
                                               const u16* __restrict__ BF,
                                               const float* __restrict__ al,
                                               const float* __restrict__ ar,
                                               u16* __restrict__ C,
                                               float* __restrict__ el,
                                               float* __restrict__ er, int M) {
    const int NKT = K / 32;
    __shared__ u16 cxpose[4][16 * 68];  // per-wave C-transpose buf (no barriers needed)
    int t = threadIdx.x;
    int wave = t >> 6, lane = t & 63;
    int l15 = lane & 15, kg = lane >> 4;
    int h = wave;                       // wave == head == col group
    int ct0 = h * 4;

    short8 breg[NKT][4];
#pragma unroll
    for (int kt = 0; kt < NKT; ++kt)
#pragma unroll
        for (int c = 0; c < 4; ++c)
            breg[kt][c] = *reinterpret_cast<const short8*>(
                              BF + (size_t)(kt * 16 + ct0 + c) * 512 + lane * 8);

    float alv[4], arv[4];
#pragma unroll
    for (int c = 0; c < 4; ++c) {
        alv[c] = al[(ct0 + c) * 16 + l15];
        arv[c] = ar[(ct0 + c) * 16 + l15];
    }

    u16* cbuf = cxpose[wave];
    for (int rt = 0; rt < 4; ++rt) {
        int row0 = bx * 64 + rt * 16;
        if (row0 >= M) break;
        int arow = row0 + l15; if (arow >= M) arow = M - 1;   // clamp; stores guarded
        const u16* Ap = A + (size_t)arow * K + kg * 8;

        floatx4 acc[4];
#pragma unroll
        for (int c = 0; c < 4; ++c) acc[c] = (floatx4)0.0f;
#pragma unroll
        for (int kt = 0; kt < NKT; ++kt) {
            short8 a = *reinterpret_cast<const short8*>(Ap + kt * 32);
#pragma unroll
            for (int c = 0; c < 4; ++c)
                acc[c] = __builtin_amdgcn_mfma_f32_16x16x32_bf16(a, breg[kt][c], acc[c], 0, 0, 0);
        }

        floatx4 pl = (floatx4)0.0f, pr = (floatx4)0.0f;
#pragma unroll
        for (int c = 0; c < 4; ++c) {
            pl += acc[c] * alv[c];
            pr += acc[c] * arv[c];
        }
#pragma unroll
        for (int off = 1; off < 16; off <<= 1) {
#pragma unroll
            for (int j = 0; j < 4; ++j) {
                pl[j] += __shfl_xor(pl[j], off);
                pr[j] += __shfl_xor(pr[j], off);
            }
        }
        if (l15 == 0) {
#pragma unroll
            for (int j = 0; j < 4; ++j) {
                int n = row0 + kg * 4 + j;
                if (n < M) { el[n * 4 + h] = pl[j]; er[n * 4 + h] = pr[j]; }
            }
        }

#pragma unroll
        for (int c = 0; c < 4; ++c)
#pragma unroll
            for (int j = 0; j < 4; ++j)
                cbuf[(kg * 4 + j) * 68 + c * 16 + l15] = f2b(acc[c][j]);
#pragma unroll
        for (int it = 0; it < 2; ++it) {
            int r = (lane >> 3) + it * 8;
            int cg = lane & 7;
            int grow = row0 + r;
            if (grow < M) {
                short8 v = *reinterpret_cast<const short8*>(cbuf + r * 68 + cg * 8);
                *reinterpret_cast<short8*>(C + (size_t)grow * 256 + h * 64 + cg * 8) = v;
            }
        }
    }
}

// ---------------- edge-weight body (CSR order, coalesced) ----------------
__device__ __forceinline__ void edge_w_body(int e, const int* __restrict__ csr_src,
                                            const int* __restrict__ csr_dst,
                                            const float* __restrict__ el,
                                            const float* __restrict__ er,
                                            float* __restrict__ w) {
    if (e >= N_EDGES) return;
    int s = csr_src[e], d = csr_dst[e];
    float4 l = *reinterpret_cast<const float4*>(&el[s * 4]);
    float4 r = *reinterpret_cast<const float4*>(&er[d * 4]);
    float4 o; float v;
    v = l.x + r.x; v = (v > 0.f) ? v : 0.2f * v; o.x = __expf(v);
    v = l.y + r.y; v = (v > 0.f) ? v : 0.2f * v; o.y = __expf(v);
    v = l.z + r.z; v = (v > 0.f) ? v : 0.2f * v; o.z = __expf(v);
    v = l.w + r.w; v = (v > 0.f) ? v : 0.2f * v; o.w = __expf(v);
    *reinterpret_cast<float4*>(&w[(size_t)e * 4]) = o;
}

// ---------------- fused gemm1 + scatter (atomic-free: pos = offs[d] + rank[e]) ----------------
__global__ __launch_bounds__(256) void gemm1_scatter_kernel(const u16* __restrict__ A,
                                                            const u16* __restrict__ BF,
                                                            const float* __restrict__ al,
                                                            const float* __restrict__ ar,
                                                            u16* __restrict__ C,
                                                            float* __restrict__ el,
                                                            float* __restrict__ er,
                                                            const int* __restrict__ src,
                                                            const int* __restrict__ dst,
                                                            const int* __restrict__ offs,
                                                            const int* __restrict__ rank,
                                                            int* __restrict__ csr_src) {
    int b = blockIdx.x;
    int g = b / 5, r = b - g * 5;
    if (r == 0) {
        gemm_attn_body<IN_DIM>(g, A, BF, al, ar, C, el, er, N_NODES);
    } else {
        int e = (b - g - 1) * 256 + threadIdx.x;
        if (e < N_EDGES) {
            int d = dst[e];
            csr_src[offs[d] + rank[e]] = src[e];   // no atomics: rank from prep's count pass
        }
    }
}

// ---------------- fused gemm2 + edge_w2 (el2/er2 already computed by gather1) ----------------
__global__ __launch_bounds__(256) void gemm2_edgew_kernel(const u16* __restrict__ A,
                                                          const u16* __restrict__ BF,
                                                          const float* __restrict__ al,
                                                          const float* __restrict__ ar,
                                                          u16* __restrict__ C,
                                                          float* __restrict__ el_dummy,
                                                          float* __restrict__ er_dummy,
                                                          const int* __restrict__ csr_src,
                                                          const int* __restrict__ csr_dst,
                                                          const float* __restrict__ el2,
                                                          const float* __restrict__ er2,
                                                          float* __restrict__ w) {
    int b = blockIdx.x;
    int g = b / 5, r = b - g * 5;
    if (r == 0) {
        gemm_attn_body<F2>(g, A, BF, al, ar, C, el_dummy, er_dummy, N_NODES);
    } else {
        int e = (b - g - 1) * 256 + threadIdx.x;
        edge_w_body(e, csr_src, csr_dst, el2, er2, w);
    }
}

// ---------------- standalone edge weights (layer 1) ----------------
__global__ void edge_w_kernel(const int* __restrict__ csr_src, const int* __restrict__ csr_dst,
                              const float* __restrict__ el, const float* __restrict__ er,
                              float* __restrict__ w) {
    edge_w_body(blockIdx.x * blockDim.x + threadIdx.x, csr_src, csr_dst, el, er, w);
}

// ---------------- gather1: aggregate + el2/er2 epilogue ----------------
// Wal2 staged in SWIZZLED LDS layout: lane l's 32 floats (rows 4l..4l+3) at offset l*33
// (+1 pad per chunk) -> bank = (l + k) % 32 -> 2-way across 64 lanes = conflict-free.
// (r16's [256][8] layout put every lane's chunk at a 128B stride -> 32-way, 12M conflicts.)
__global__ __launch_bounds__(256) void gather1_kernel(const u16* __restrict__ feat,
                                                      const float* __restrict__ w,
                                                      const int* __restrict__ offs,
                                                      const int* __restrict__ csr_src,
                                                      const float* __restrict__ bias,
                                                      const float* __restrict__ Wal2,
                                                      u16* __restrict__ outb,
                                                      float* __restrict__ el2,
                                                      float* __restrict__ er2) {
    __shared__ float wal[64 * 33];      // swizzled: chunk l at l*33, 32 payload + 1 pad
    {
        int t = threadIdx.x;
#pragma unroll
        for (int u = 0; u < 8; ++u) {
            int j = t * 8 + u;          // 0..2047 linear over Wal2
            wal[(j >> 5) * 33 + (j & 31)] = Wal2[j];
        }
    }
    __syncthreads();
    int n = blockIdx.x * 4 + (threadIdx.x >> 6);
    if (n >= N_NODES) return;
    int lane = threadIdx.x & 63;
    int h = lane >> 4;
    const ushort4* feat4 = reinterpret_cast<const ushort4*>(feat);
    int s0 = offs[n], s1 = offs[n + 1];
    float4 acc = make_float4(0.f, 0.f, 0.f, 0.f);
    float den = 0.f;
    int i = s0;
    for (; i + 4 <= s1; i += 4) {
        int n0 = csr_src[i], n1 = csr_src[i + 1], n2 = csr_src[i + 2], n3 = csr_src[i + 3];
        float x0 = w[(size_t)(i + 0) * 4 + h];
        float x1 = w[(size_t)(i + 1) * 4 + h];
        float x2 = w[(size_t)(i + 2) * 4 + h];
        float x3 = w[(size_t)(i + 3) * 4 + h];
        ushort4 f0 = feat4[(size_t)n0 * 64 + lane];
        ushort4 f1 = feat4[(size_t)n1 * 64 + lane];
        ushort4 f2 = feat4[(size_t)n2 * 64 + lane];
        ushort4 f3 = feat4[(size_t)n3 * 64 + lane];
        acc.x = fmaf(x0, bf2f(f0.x), acc.x); acc.y = fmaf(x0, bf2f(f0.y), acc.y);
        acc.z = fmaf(x0, bf2f(f0.z), acc.z); acc.w = fmaf(x0, bf2f(f0.w), acc.w);
        acc.x = fmaf(x1, bf2f(f1.x), acc.x); acc.y = fmaf(x1, bf2f(f1.y), acc.y);
        acc.z = fmaf(x1, bf2f(f1.z), acc.z); acc.w = fmaf(x1, bf2f(f1.w), acc.w);
        acc.x = fmaf(x2, bf2f(f2.x), acc.x); acc.y = fmaf(x2, bf2f(f2.y), acc.y);
        acc.z = fmaf(x2, bf2f(f2.z), acc.z); acc.w = fmaf(x2, bf2f(f2.w), acc.w);
        acc.x = fmaf(x3, bf2f(f3.x), acc.x); acc.y = fmaf(x3, bf2f(f3.y), acc.y);
        acc.z = fmaf(x3, bf2f(f3.z), acc.z); acc.w = fmaf(x3, bf2f(f3.w), acc.w);
        den += (x0 + x1) + (x2 + x3);
    }
    for (; i < s1; ++i) {
        int s = csr_src[i];
        float x = w[(size_t)i * 4 + h];
        ushort4 f = feat4[(size_t)s * 64 + lane];
        acc.x = fmaf(x, bf2f(f.x), acc.x); acc.y = fmaf(x, bf2f(f.y), acc.y);
        acc.z = fmaf(x, bf2f(f.z), acc.z); acc.w = fmaf(x, bf2f(f.w), acc.w);
        den += x;
    }
    float inv = (s1 > s0) ? 1.f / den : 0.f;
    float4 bv = reinterpret_cast<const float4*>(bias)[lane];
    float4 rr;
    rr.x = fmaxf(fmaf(acc.x, inv, bv.x), 0.f);
    rr.y = fmaxf(fmaf(acc.y, inv, bv.y), 0.f);
    rr.z = fmaxf(fmaf(acc.z, inv, bv.z), 0.f);
    rr.w = fmaxf(fmaf(acc.w, inv, bv.w), 0.f);
    ushort4 o;
    o.x = f2b(rr.x); o.y = f2b(rr.y); o.z = f2b(rr.z); o.w = f2b(rr.w);
    reinterpret_cast<ushort4*>(outb)[(size_t)n * 64 + lane] = o;

    // ---- el2/er2 epilogue: 8 full-wave dots (swizzled LDS, conflict-free) ----
    const float* wl = &wal[lane * 33];
    float p[8];
#pragma unroll
    for (int q = 0; q < 8; ++q)
        p[q] = rr.x * wl[q] + rr.y * wl[8 + q] + rr.z * wl[16 + q] + rr.w * wl[24 + q];
#pragma unroll
    for (int off = 1; off < 64; off <<= 1)
#pragma unroll
        for (int q = 0; q < 8; ++q) p[q] += __shfl_xor(p[q], off);
    if (lane == 0) {
        float4 evl = make_float4(p[0], p[2], p[4], p[6]);
        float4 evr = make_float4(p[1], p[3], p[5], p[7]);
        *reinterpret_cast<float4*>(&el2[n * 4]) = evl;
        *reinterpret_cast<float4*>(&er2[n * 4]) = evr;
    }
}

// ---------------- gather2: aggregate only ----------------
__global__ __launch_bounds__(256) void gather_kernel(const u16* __restrict__ feat,
                                                     const float* __restrict__ w,
                                                     const int* __restrict__ offs,
                                                     const int* __restrict__ csr_src,
                                                     const float* __restrict__ bias,
                                                     u16* __restrict__ outb) {
    int n = blockIdx.x * 4 + (threadIdx.x >> 6);
    if (n >= N_NODES) return;
    int lane = threadIdx.x & 63;
    int h = lane >> 4;
    const ushort4* feat4 = reinterpret_cast<const ushort4*>(feat);
    int s0 = offs[n], s1 = offs[n + 1];
    float4 acc = make_float4(0.f, 0.f, 0.f, 0.f);
    float den = 0.f;
    int i = s0;
    for (; i + 4 <= s1; i += 4) {
        int n0 = csr_src[i], n1 = csr_src[i + 1], n2 = csr_src[i + 2], n3 = csr_src[i + 3];
        float x0 = w[(size_t)(i + 0) * 4 + h];
        float x1 = w[(size_t)(i + 1) * 4 + h];
        float x2 = w[(size_t)(i + 2) * 4 + h];
        float x3 = w[(size_t)(i + 3) * 4 + h];
        ushort4 f0 = feat4[(size_t)n0 * 64 + lane];
        ushort4 f1 = feat4[(size_t)n1 * 64 + lane];
        ushort4 f2 = feat4[(size_t)n2 * 64 + lane];
        ushort4 f3 = feat4[(size_t)n3 * 64 + lane];
        acc.x = fmaf(x0, bf2f(f0.x), acc.x); acc.y = fmaf(x0, bf2f(f0.y), acc.y);
        acc.z = fmaf(x0, bf2f(f0.z), acc.z); acc.w = fmaf(x0, bf2f(f0.w), acc.w);
        acc.x = fmaf(x1, bf2f(f1.x), acc.x); acc.y = fmaf(x1, bf2f(f1.y), acc.y);
        acc.z = fmaf(x1, bf2f(f1.z), acc.z); acc.w = fmaf(x1, bf2f(f1.w), acc.w);
        acc.x = fmaf(x2, bf2f(f2.x), acc.x); acc.y = fmaf(x2, bf2f(f2.y), acc.y);
        acc.z = fmaf(x2, bf2f(f2.z), acc.z); acc.w = fmaf(x2, bf2f(f2.w), acc.w);
        acc.x = fmaf(x3, bf2f(f3.x), acc.x); acc.y = fmaf(x3, bf2f(f3.y), acc.y);
        acc.z = fmaf(x3, bf2f(f3.z), acc.z); acc.w = fmaf(x3, bf2f(f3.w), acc.w);
        den += (x0 + x1) + (x2 + x3);
    }
    for (; i < s1; ++i) {
        int s = csr_src[i];
        float x = w[(size_t)i * 4 + h];
        ushort4 f = feat4[(size_t)s * 64 + lane];
        acc.x = fmaf(x, bf2f(f.x), acc.x); acc.y = fmaf(x, bf2f(f.y), acc.y);
        acc.z = fmaf(x, bf2f(f.z), acc.z); acc.w = fmaf(x, bf2f(f.w), acc.w);
        den += x;
    }
    float inv = (s1 > s0) ? 1.f / den : 0.f;
    float4 bv = reinterpret_cast<const float4*>(bias)[lane];
    ushort4 o;
    o.x = f2b(fmaxf(fmaf(acc.x, inv, bv.x), 0.f));
    o.y = f2b(fmaxf(fmaf(acc.y, inv, bv.y), 0.f));
    o.z = f2b(fmaxf(fmaf(acc.z, inv, bv.z), 0.f));
    o.w = f2b(fmaxf(fmaf(acc.w, inv, bv.w), 0.f));
    reinterpret_cast<ushort4*>(outb)[(size_t)n * 64 + lane] = o;
}

// ---------------- fused mean-pool + 3-layer MLP head (bf16 h2) ----------------
__global__ __launch_bounds__(256) void head_kernel(const u16* __restrict__ h2,
                                                   const float* __restrict__ desc,
                                                   const float* __restrict__ fc1_w,
                                                   const float* __restrict__ fc1_b,
                                                   const float* __restrict__ fc2_w,
                                                   const float* __restrict__ fc2_b,
                                                   const float* __restrict__ out_w,
                                                   const float* __restrict__ out_b,
                                                   float* __restrict__ out) {
    __shared__ float comb[288];
    __shared__ float z1[64];
    __shared__ float z2[32];
    int g = blockIdx.x, t = threadIdx.x;
    const u16* base = h2 + (size_t)g * NODES_PER_GRAPH * 256;
    float s0 = 0.f, s1 = 0.f, s2 = 0.f, s3 = 0.f;   // 4 independent load chains
    for (int i = 0; i < NODES_PER_GRAPH; i += 4) {
        s0 += bf2f(base[(size_t)(i + 0) * 256 + t]);
        s1 += bf2f(base[(size_t)(i + 1) * 256 + t]);
        s2 += bf2f(base[(size_t)(i + 2) * 256 + t]);
        s3 += bf2f(base[(size_t)(i + 3) * 256 + t]);
    }
    comb[t] = ((s0 + s1) + (s2 + s3)) * (1.f / NODES_PER_GRAPH);
    if (t < EXTRA) comb[256 + t] = desc[g * EXTRA + t];
    __syncthreads();
    if (t < 64) {
        float a = fc1_b[t];
        for (int i = 0; i < 288; ++i) a += comb[i] * fc1_w[i * 64 + t];
        z1[t] = fmaxf(a, 0.f);
    }
    __syncthreads();
    if (t < 32) {
        float a = fc2_b[t];
        for (int i = 0; i < 64; ++i) a += z1[i] * fc2_w[i * 32 + t];
        z2[t] = fmaxf(a, 0.f);
    }
    __syncthreads();
    if (t == 0) {
        float a = out_b[0];
        for (int i = 0; i < 32; ++i) a += z2[i] * out_w[i];
        out[g] = a;
    }
}

extern "C" void kernel_launch(void* const* d_in, const int* in_sizes, int n_in,
                              void* d_out, int out_size, void* d_ws, size_t ws_size,
                              hipStream_t stream) {
    const float* x     = (const float*)d_in[0];
    const float* desc  = (const float*)d_in[1];
    const int*   src   = (const int*)d_in[2];
    const int*   dst   = (const int*)d_in[3];
    /* d_in[4] graph_id: contiguous (n/100) by construction — unused */
    const float* W1    = (const float*)d_in[5];
    const float* al1   = (const float*)d_in[6];
    const float* ar1   = (const float*)d_in[7];
    const float* b1    = (const float*)d_in[8];
    const float* W2    = (const float*)d_in[9];
    const float* al2   = (const float*)d_in[10];
    const float* ar2   = (const float*)d_in[11];
    const float* b2    = (const float*)d_in[12];
    const float* fc1_w = (const float*)d_in[13];
    const float* fc1_b = (const float*)d_in[14];
    const float* fc2_w = (const float*)d_in[15];
    const float* fc2_b = (const float*)d_in[16];
    const float* out_w = (const float*)d_in[17];
    const float* out_b = (const float*)d_in[18];
    float* out = (float*)d_out;

    char* ws = (char*)d_ws;
    size_t off = 0;
    auto alloc = [&](size_t bytes) -> void* {
        void* p = ws + off;
        off = (off + bytes + 255) & ~(size_t)255;
        return p;
    };
    u16*   xb      = (u16*)alloc((size_t)N_NODES * IN_DIM * 2);
    u16*   featb   = (u16*)alloc((size_t)N_NODES * 256 * 2);
    u16*   h1b     = (u16*)alloc((size_t)N_NODES * 256 * 2);
    u16*   h2b     = (u16*)alloc((size_t)N_NODES * 256 * 2);
    u16*   BF1     = (u16*)alloc((size_t)IN_DIM * 256 * 2);
    u16*   BF2     = (u16*)alloc((size_t)F2 * 256 * 2);
    float* el      = (float*)alloc((size_t)N_NODES * 4 * 4);
    float* er      = (float*)alloc((size_t)N_NODES * 4 * 4);
    float* el2     = (float*)alloc((size_t)N_NODES * 4 * 4);
    float* er2     = (float*)alloc((size_t)N_NODES * 4 * 4);
    float* Wal2    = (float*)alloc((size_t)256 * 8 * 4);
    int*   offs    = (int*)alloc((size_t)(N_NODES + 1) * 4);
    int*   cnt     = (int*)alloc((size_t)N_NODES * 4);
    int*   part    = (int*)alloc((size_t)N_NODES * 4);
    int*   bsum    = (int*)alloc(64 * 4);
    int*   csr_src = (int*)alloc((size_t)N_EDGES * 4);
    int*   csr_dst = (int*)alloc((size_t)N_EDGES * 4);
    int*   rankb   = (int*)alloc((size_t)N_EDGES * 4);
    float* wbuf    = (float*)alloc((size_t)N_EDGES * 4 * 4);

    hipMemsetAsync(cnt, 0, (size_t)N_NODES * 4, stream);
    prep0_kernel<<<1, 256, 0, stream>>>(W2, al2, ar2, Wal2);
    prep_kernel<<<CNT_BLK + CVT_BLK + RP1_BLK + RP2_BLK, 256, 0, stream>>>(
        dst, cnt, rankb, x, xb, W1, BF1, W2, BF2);
    scan_block_kernel<<<SCAN_BLOCKS, 1024, 0, stream>>>(cnt, part, bsum);
    scan_finalize_kernel<<<SCAN_BLOCKS, 1024, 0, stream>>>(part, bsum, offs, csr_dst);

    int eb = (N_EDGES + 255) / 256;
    int ngb = (N_NODES + 3) / 4;
    // layer 1: gemm1 overlapped with atomic-free CSR scatter
    gemm1_scatter_kernel<<<GEMM_BLKS + SCAT_BLKS, 256, 0, stream>>>(
        xb, BF1, al1, ar1, featb, el, er, src, dst, offs, rankb, csr_src);
    edge_w_kernel<<<eb, 256, 0, stream>>>(csr_src, csr_dst, el, er, wbuf);
    gather1_kernel<<<ngb, 256, 0, stream>>>(featb, wbuf, offs, csr_src, b1, Wal2,
                                            h1b, el2, er2);
    // layer 2: gemm2 overlapped with edge_w2 (el2/er2 from gather1)
    gemm2_edgew_kernel<<<GEMM_BLKS + SCAT_BLKS, 256, 0, stream>>>(
        h1b, BF2, al2, ar2, featb, el, er, csr_src, csr_dst, el2, er2, wbuf);
    gather_kernel<<<ngb, 256, 0, stream>>>(featb, wbuf, offs, csr_src, b2, h2b);
    // pool + MLP head
    head_kernel<<<N_GRAPHS, 256, 0, stream>>>(h2b, desc, fc1_w, fc1_b, fc2_w, fc2_b,
                                              out_w, out_b, out);
}

// Round 18
// 257.192 us; speedup vs baseline: 1.1446x; 1.0944x over previous
//
#include <hip/hip_runtime.h>
#include <hip/hip_bf16.h>

#define N_NODES 50000
#define N_EDGES 800000
#define N_GRAPHS 500
#define IN_DIM 128
#define EXTRA 32
#define HID 64
#define HEADS 4
#define F2 256   /* HEADS*HID */
#define NODES_PER_GRAPH 100
#define SCAN_BLOCKS ((N_NODES + 1023) / 1024)   /* 49 */
#define GEMM1_BLKS 782                           /* ceil(50000/64) */
#define SCAT_BLKS 3125                           /* ceil(800000/256) */

typedef unsigned short u16;
typedef __attribute__((ext_vector_type(8))) short short8;     // 8 bf16 = 4 VGPR
typedef __attribute__((ext_vector_type(4))) float floatx4;    // MFMA C/D frag

__device__ __forceinline__ float bf2f(u16 u) {
    union { unsigned int i; float f; } v;
    v.i = ((unsigned int)u) << 16;
    return v.f;
}
__device__ __forceinline__ u16 f2b(float f) {
    __hip_bfloat16 h = __float2bfloat16(f);
    return *reinterpret_cast<u16*>(&h);
}

// ---------------- fused prep: edge-count+rank | x->bf16 | W1/W2 repack ----------------
// The count atomicAdd's RETURN VALUE is the edge's rank within its dst segment —
// stored coalesced so the later scatter needs no second atomic pass.
#define CNT_BLK 3125
#define CVT_BLK 6250
#define RP1_BLK 16
#define RP2_BLK 32
__global__ __launch_bounds__(256) void prep_kernel(const int* __restrict__ dst,
                                                   int* __restrict__ cnt,
                                                   int* __restrict__ rank,
                                                   const float* __restrict__ x,
                                                   u16* __restrict__ xb,
                                                   const float* __restrict__ W1,
                                                   u16* __restrict__ BF1,
                                                   const float* __restrict__ W2,
                                                   u16* __restrict__ BF2) {
    int b = blockIdx.x, t = threadIdx.x;
    if (b < CNT_BLK) {
        int e = b * 256 + t;
        if (e < N_EDGES) rank[e] = atomicAdd(&cnt[dst[e]], 1);
    } else if (b < CNT_BLK + CVT_BLK) {
        int i = (b - CNT_BLK) * 256 + t;   // float4 index
        float4 v = reinterpret_cast<const float4*>(x)[i];
        ushort4 o;
        o.x = f2b(v.x); o.y = f2b(v.y); o.z = f2b(v.z); o.w = f2b(v.w);
        reinterpret_cast<ushort4*>(xb)[i] = o;
    } else {
        const float* W;
        u16* BF;
        int chunk;
        if (b < CNT_BLK + CVT_BLK + RP1_BLK) {
            W = W1; BF = BF1; chunk = (b - CNT_BLK - CVT_BLK) * 4 + (t >> 6);
        } else {
            W = W2; BF = BF2; chunk = (b - CNT_BLK - CVT_BLK - RP1_BLK) * 4 + (t >> 6);
        }
        int l = t & 63;
        int kt = chunk >> 4, ct = chunk & 15;
        int col = ct * 16 + (l & 15);
        int k0 = kt * 32 + 8 * (l >> 4);
        u16* p = BF + (size_t)chunk * 512 + l * 8;
#pragma unroll
        for (int j = 0; j < 8; ++j) p[j] = f2b(W[(size_t)(k0 + j) * 256 + col]);
    }
}

// ---------------- CSR scan ----------------
__global__ __launch_bounds__(1024) void scan_block_kernel(const int* __restrict__ cnt,
                                                          int* __restrict__ part,
                                                          int* __restrict__ bsum) {
    __shared__ int buf[1024];
    int b = blockIdx.x, t = threadIdx.x;
    int i = b * 1024 + t;
    buf[t] = (i < N_NODES) ? cnt[i] : 0;
    __syncthreads();
    for (int d = 1; d < 1024; d <<= 1) {
        int add = (t >= d) ? buf[t - d] : 0;
        __syncthreads();
        buf[t] += add;
        __syncthreads();
    }
    if (i < N_NODES) part[i] = buf[t];
    if (t == 1023) bsum[b] = buf[t];
}

// finalize offs AND fill csr_dst (each thread fills its node's contiguous segment)
__global__ __launch_bounds__(1024) void scan_finalize_kernel(const int* __restrict__ part,
                                                             const int* __restrict__ bsum,
                                                             int* __restrict__ offs,
                                                             int* __restrict__ csr_dst) {
    __shared__ int sb;
    int t = threadIdx.x;
    if (t < 64) {
        int v = (t < blockIdx.x) ? bsum[t] : 0;   // SCAN_BLOCKS=49 <= 64
#pragma unroll
        for (int d = 32; d > 0; d >>= 1) v += __shfl_xor(v, d);
        if (t == 0) sb = v;
    }
    __syncthreads();
    int sbase = sb;
    int i = blockIdx.x * 1024 + t;
    if (i < N_NODES) {
        int hi = part[i] + sbase;
        offs[i + 1] = hi;
        if (i == 0) offs[0] = 0;
        int lo = (t == 0) ? sbase : part[i - 1] + sbase;
        for (int p = lo; p < hi; ++p) csr_dst[p] = i;   // contiguous per-node segment
    }
}

// ---------------- MFMA GEMM + attention epilogue body (register-resident B) ----------------
template <int K>
__device__ __forceinline__ void gemm_attn_body(int bx, const u16* __restrict__ A,
                                               const u16* __restrict__ BF,
                                               const float* __restrict__ al,
                                               const float* __restrict__ ar,
                                               u16* __restrict__ C,
                                               float* __restrict__ el,
                                               float* __restrict__ er, int M) {
    const int NKT = K / 32;
    __shared__ u16 cxpose[4][16 * 68];  // per-wave C-transpose buf (no barriers needed)
    int t = threadIdx.x;
    int wave = t >> 6, lane = t & 63;
    int l15 = lane & 15, kg = lane >> 4;
    int h = wave;                       // wave == head == col group
    int ct0 = h * 4;

    short8 breg[NKT][4];
#pragma unroll
    for (int kt = 0; kt < NKT; ++kt)
#pragma unroll
        for (int c = 0; c < 4; ++c)
            breg[kt][c] = *reinterpret_cast<const short8*>(
                              BF + (size_t)(kt * 16 + ct0 + c) * 512 + lane * 8);

    float alv[4], arv[4];
#pragma unroll
    for (int c = 0; c < 4; ++c) {
        alv[c] = al[(ct0 + c) * 16 + l15];
        arv[c] = ar[(ct0 + c) * 16 + l15];
    }

    u16* cbuf = cxpose[wave];
    for (int rt = 0; rt < 4; ++rt) {
        int row0 = bx * 64 + rt * 16;
        if (row0 >= M) break;
        int arow = row0 + l15; if (arow >= M) arow = M - 1;   // clamp; stores guarded
        const u16* Ap = A + (size_t)arow * K + kg * 8;

        floatx4 acc[4];
#pragma unroll
        for (int c = 0; c < 4; ++c) acc[c] = (floatx4)0.0f;
#pragma unroll
        for (int kt = 0; kt < NKT; ++kt) {
            short8 a = *reinterpret_cast<const short8*>(Ap + kt * 32);
#pragma unroll
            for (int c = 0; c < 4; ++c)
                acc[c] = __builtin_amdgcn_mfma_f32_16x16x32_bf16(a, breg[kt][c], acc[c], 0, 0, 0);
        }

        floatx4 pl = (floatx4)0.0f, pr = (floatx4)0.0f;
#pragma unroll
        for (int c = 0; c < 4; ++c) {
            pl += acc[c] * alv[c];
            pr += acc[c] * arv[c];
        }
#pragma unroll
        for (int off = 1; off < 16; off <<= 1) {
#pragma unroll
            for (int j = 0; j < 4; ++j) {
                pl[j] += __shfl_xor(pl[j], off);
                pr[j] += __shfl_xor(pr[j], off);
            }
        }
        if (l15 == 0) {
#pragma unroll
            for (int j = 0; j < 4; ++j) {
                int n = row0 + kg * 4 + j;
                if (n < M) { el[n * 4 + h] = pl[j]; er[n * 4 + h] = pr[j]; }
            }
        }

#pragma unroll
        for (int c = 0; c < 4; ++c)
#pragma unroll
            for (int j = 0; j < 4; ++j)
                cbuf[(kg * 4 + j) * 68 + c * 16 + l15] = f2b(acc[c][j]);
#pragma unroll
        for (int it = 0; it < 2; ++it) {
            int r = (lane >> 3) + it * 8;
            int cg = lane & 7;
            int grow = row0 + r;
            if (grow < M) {
                short8 v = *reinterpret_cast<const short8*>(cbuf + r * 68 + cg * 8);
                *reinterpret_cast<short8*>(C + (size_t)grow * 256 + h * 64 + cg * 8) = v;
            }
        }
    }
}

// ---------------- fused gemm1 + scatter (atomic-free: pos = offs[d] + rank[e]) ----------------
__global__ __launch_bounds__(256) void gemm1_scatter_kernel(const u16* __restrict__ A,
                                                            const u16* __restrict__ BF,
                                                            const float* __restrict__ al,
                                                            const float* __restrict__ ar,
                                                            u16* __restrict__ C,
                                                            float* __restrict__ el,
                                                            float* __restrict__ er,
                                                            const int* __restrict__ src,
                                                            const int* __restrict__ dst,
                                                            const int* __restrict__ offs,
                                                            const int* __restrict__ rank,
                                                            int* __restrict__ csr_src) {
    int b = blockIdx.x;
    int g = b / 5, r = b - g * 5;
    if (r == 0) {                        // g in [0, 782) since grid = 3907
        gemm_attn_body<IN_DIM>(g, A, BF, al, ar, C, el, er, N_NODES);
    } else {
        int e = (b - g - 1) * 256 + threadIdx.x;   // scatter id = b - g - 1 in [0, 3125)
        if (e < N_EDGES) {
            int d = dst[e];
            csr_src[offs[d] + rank[e]] = src[e];   // no atomics: rank from prep's count pass
        }
    }
}

// ---------------- standalone gemm (layer 2) ----------------
template <int K>
__global__ __launch_bounds__(256) void gemm_mfma_attn_kernel(const u16* __restrict__ A,
                                                             const u16* __restrict__ BF,
                                                             const float* __restrict__ al,
                                                             const float* __restrict__ ar,
                                                             u16* __restrict__ C,
                                                             float* __restrict__ el,
                                                             float* __restrict__ er, int M) {
    gemm_attn_body<K>(blockIdx.x, A, BF, al, ar, C, el, er, M);
}

// ---------------- edge weights, CSR order, AoS w[p][h] ----------------
__global__ void edge_w_kernel(const int* __restrict__ csr_src, const int* __restrict__ csr_dst,
                              const float* __restrict__ el, const float* __restrict__ er,
                              float* __restrict__ w) {
    int p = blockIdx.x * blockDim.x + threadIdx.x;
    if (p >= N_EDGES) return;
    int s = csr_src[p], d = csr_dst[p];
    float4 l = *reinterpret_cast<const float4*>(&el[s * 4]);
    float4 r = *reinterpret_cast<const float4*>(&er[d * 4]);
    float4 o; float v;
    v = l.x + r.x; v = (v > 0.f) ? v : 0.2f * v; o.x = __expf(v);
    v = l.y + r.y; v = (v > 0.f) ? v : 0.2f * v; o.y = __expf(v);
    v = l.z + r.z; v = (v > 0.f) ? v : 0.2f * v; o.z = __expf(v);
    v = l.w + r.w; v = (v > 0.f) ? v : 0.2f * v; o.w = __expf(v);
    *reinterpret_cast<float4*>(&w[(size_t)p * 4]) = o;
}

// ---------------- aggregate: wave per node, precomputed weights, bf16 feat rows ----------------
__global__ __launch_bounds__(256) void gather_kernel(const u16* __restrict__ feat,
                                                     const float* __restrict__ w,
                                                     const int* __restrict__ offs,
                                                     const int* __restrict__ csr_src,
                                                     const float* __restrict__ bias,
                                                     u16* __restrict__ outb) {
    int n = blockIdx.x * 4 + (threadIdx.x >> 6);
    if (n >= N_NODES) return;
    int lane = threadIdx.x & 63;
    int h = lane >> 4;                       // lane*4 = h*64 + (lane&15)*4
    const ushort4* feat4 = reinterpret_cast<const ushort4*>(feat);
    int s0 = offs[n], s1 = offs[n + 1];
    float4 acc = make_float4(0.f, 0.f, 0.f, 0.f);
    float den = 0.f;
    int i = s0;
    for (; i + 4 <= s1; i += 4) {            // 4 feat rows in flight
        int n0 = csr_src[i], n1 = csr_src[i + 1], n2 = csr_src[i + 2], n3 = csr_src[i + 3];
        float x0 = w[(size_t)(i + 0) * 4 + h];
        float x1 = w[(size_t)(i + 1) * 4 + h];
        float x2 = w[(size_t)(i + 2) * 4 + h];
        float x3 = w[(size_t)(i + 3) * 4 + h];
        ushort4 f0 = feat4[(size_t)n0 * 64 + lane];
        ushort4 f1 = feat4[(size_t)n1 * 64 + lane];
        ushort4 f2 = feat4[(size_t)n2 * 64 + lane];
        ushort4 f3 = feat4[(size_t)n3 * 64 + lane];
        acc.x = fmaf(x0, bf2f(f0.x), acc.x); acc.y = fmaf(x0, bf2f(f0.y), acc.y);
        acc.z = fmaf(x0, bf2f(f0.z), acc.z); acc.w = fmaf(x0, bf2f(f0.w), acc.w);
        acc.x = fmaf(x1, bf2f(f1.x), acc.x); acc.y = fmaf(x1, bf2f(f1.y), acc.y);
        acc.z = fmaf(x1, bf2f(f1.z), acc.z); acc.w = fmaf(x1, bf2f(f1.w), acc.w);
        acc.x = fmaf(x2, bf2f(f2.x), acc.x); acc.y = fmaf(x2, bf2f(f2.y), acc.y);
        acc.z = fmaf(x2, bf2f(f2.z), acc.z); acc.w = fmaf(x2, bf2f(f2.w), acc.w);
        acc.x = fmaf(x3, bf2f(f3.x), acc.x); acc.y = fmaf(x3, bf2f(f3.y), acc.y);
        acc.z = fmaf(x3, bf2f(f3.z), acc.z); acc.w = fmaf(x3, bf2f(f3.w), acc.w);
        den += (x0 + x1) + (x2 + x3);
    }
    for (; i < s1; ++i) {
        int s = csr_src[i];
        float x = w[(size_t)i * 4 + h];
        ushort4 f = feat4[(size_t)s * 64 + lane];
        acc.x = fmaf(x, bf2f(f.x), acc.x); acc.y = fmaf(x, bf2f(f.y), acc.y);
        acc.z = fmaf(x, bf2f(f.z), acc.z); acc.w = fmaf(x, bf2f(f.w), acc.w);
        den += x;
    }
    float inv = (s1 > s0) ? 1.f / den : 0.f;
    float4 bv = reinterpret_cast<const float4*>(bias)[lane];
    ushort4 o;
    o.x = f2b(fmaxf(fmaf(acc.x, inv, bv.x), 0.f));
    o.y = f2b(fmaxf(fmaf(acc.y, inv, bv.y), 0.f));
    o.z = f2b(fmaxf(fmaf(acc.z, inv, bv.z), 0.f));
    o.w = f2b(fmaxf(fmaf(acc.w, inv, bv.w), 0.f));
    reinterpret_cast<ushort4*>(outb)[(size_t)n * 64 + lane] = o;
}

// ---------------- fused mean-pool + 3-layer MLP head (bf16 h2) ----------------
__global__ __launch_bounds__(256) void head_kernel(const u16* __restrict__ h2,
                                                   const float* __restrict__ desc,
                                                   const float* __restrict__ fc1_w,
                                                   const float* __restrict__ fc1_b,
                                                   const float* __restrict__ fc2_w,
                                                   const float* __restrict__ fc2_b,
                                                   const float* __restrict__ out_w,
                                                   const float* __restrict__ out_b,
                                                   float* __restrict__ out) {
    __shared__ float comb[288];
    __shared__ float z1[64];
    __shared__ float z2[32];
    int g = blockIdx.x, t = threadIdx.x;
    const u16* base = h2 + (size_t)g * NODES_PER_GRAPH * 256;
    float s0 = 0.f, s1 = 0.f, s2 = 0.f, s3 = 0.f;   // 4 independent load chains
    for (int i = 0; i < NODES_PER_GRAPH; i += 4) {
        s0 += bf2f(base[(size_t)(i + 0) * 256 + t]);
        s1 += bf2f(base[(size_t)(i + 1) * 256 + t]);
        s2 += bf2f(base[(size_t)(i + 2) * 256 + t]);
        s3 += bf2f(base[(size_t)(i + 3) * 256 + t]);
    }
    comb[t] = ((s0 + s1) + (s2 + s3)) * (1.f / NODES_PER_GRAPH);
    if (t < EXTRA) comb[256 + t] = desc[g * EXTRA + t];
    __syncthreads();
    if (t < 64) {
        float a = fc1_b[t];
        for (int i = 0; i < 288; ++i) a += comb[i] * fc1_w[i * 64 + t];
        z1[t] = fmaxf(a, 0.f);
    }
    __syncthreads();
    if (t < 32) {
        float a = fc2_b[t];
        for (int i = 0; i < 64; ++i) a += z1[i] * fc2_w[i * 32 + t];
        z2[t] = fmaxf(a, 0.f);
    }
    __syncthreads();
    if (t == 0) {
        float a = out_b[0];
        for (int i = 0; i < 32; ++i) a += z2[i] * out_w[i];
        out[g] = a;
    }
}

extern "C" void kernel_launch(void* const* d_in, const int* in_sizes, int n_in,
                              void* d_out, int out_size, void* d_ws, size_t ws_size,
                              hipStream_t stream) {
    const float* x     = (const float*)d_in[0];
    const float* desc  = (const float*)d_in[1];
    const int*   src   = (const int*)d_in[2];
    const int*   dst   = (const int*)d_in[3];
    /* d_in[4] graph_id: contiguous (n/100) by construction — unused */
    const float* W1    = (const float*)d_in[5];
    const float* al1   = (const float*)d_in[6];
    const float* ar1   = (const float*)d_in[7];
    const float* b1    = (const float*)d_in[8];
    const float* W2    = (const float*)d_in[9];
    const float* al2   = (const float*)d_in[10];
    const float* ar2   = (const float*)d_in[11];
    const float* b2    = (const float*)d_in[12];
    const float* fc1_w = (const float*)d_in[13];
    const float* fc1_b = (const float*)d_in[14];
    const float* fc2_w = (const float*)d_in[15];
    const float* fc2_b = (const float*)d_in[16];
    const float* out_w = (const float*)d_in[17];
    const float* out_b = (const float*)d_in[18];
    float* out = (float*)d_out;

    char* ws = (char*)d_ws;
    size_t off = 0;
    auto alloc = [&](size_t bytes) -> void* {
        void* p = ws + off;
        off = (off + bytes + 255) & ~(size_t)255;
        return p;
    };
    u16*   xb      = (u16*)alloc((size_t)N_NODES * IN_DIM * 2);
    u16*   featb   = (u16*)alloc((size_t)N_NODES * 256 * 2);
    u16*   h1b     = (u16*)alloc((size_t)N_NODES * 256 * 2);
    u16*   h2b     = (u16*)alloc((size_t)N_NODES * 256 * 2);
    u16*   BF1     = (u16*)alloc((size_t)IN_DIM * 256 * 2);
    u16*   BF2     = (u16*)alloc((size_t)F2 * 256 * 2);
    float* el      = (float*)alloc((size_t)N_NODES * 4 * 4);
    float* er      = (float*)alloc((size_t)N_NODES * 4 * 4);
    int*   offs    = (int*)alloc((size_t)(N_NODES + 1) * 4);
    int*   cnt     = (int*)alloc((size_t)N_NODES * 4);
    int*   part    = (int*)alloc((size_t)N_NODES * 4);
    int*   bsum    = (int*)alloc(64 * 4);
    int*   csr_src = (int*)alloc((size_t)N_EDGES * 4);
    int*   csr_dst = (int*)alloc((size_t)N_EDGES * 4);
    int*   rankb   = (int*)alloc((size_t)N_EDGES * 4);
    float* wbuf    = (float*)alloc((size_t)N_EDGES * 4 * 4);

    hipMemsetAsync(cnt, 0, (size_t)N_NODES * 4, stream);
    prep_kernel<<<CNT_BLK + CVT_BLK + RP1_BLK + RP2_BLK, 256, 0, stream>>>(
        dst, cnt, rankb, x, xb, W1, BF1, W2, BF2);
    scan_block_kernel<<<SCAN_BLOCKS, 1024, 0, stream>>>(cnt, part, bsum);
    scan_finalize_kernel<<<SCAN_BLOCKS, 1024, 0, stream>>>(part, bsum, offs, csr_dst);

    int eb = (N_EDGES + 255) / 256;
    int ngb = (N_NODES + 3) / 4;
    // layer 1: gemm1 overlapped with atomic-free CSR scatter
    gemm1_scatter_kernel<<<GEMM1_BLKS + SCAT_BLKS, 256, 0, stream>>>(
        xb, BF1, al1, ar1, featb, el, er, src, dst, offs, rankb, csr_src);
    edge_w_kernel<<<eb, 256, 0, stream>>>(csr_src, csr_dst, el, er, wbuf);
    gather_kernel<<<ngb, 256, 0, stream>>>(featb, wbuf, offs, csr_src, b1, h1b);
    // layer 2
    gemm_mfma_attn_kernel<F2><<<(N_NODES + 63) / 64, 256, 0, stream>>>(
        h1b, BF2, al2, ar2, featb, el, er, N_NODES);
    edge_w_kernel<<<eb, 256, 0, stream>>>(csr_src, csr_dst, el, er, wbuf);
    gather_kernel<<<ngb, 256, 0, stream>>>(featb, wbuf, offs, csr_src, b2, h2b);
    // pool + MLP head
    head_kernel<<<N_GRAPHS, 256, 0, stream>>>(h2b, desc, fc1_w, fc1_b, fc2_w, fc2_b,
                                              out_w, out_b, out);
}